// Round 13
// baseline (106.500 us; speedup 1.0000x reference)
//
#include <hip/hip_runtime.h>

#define BATCH 128

constexpr float DM = 0.95122942450071400910f;  // exp(-1/20)
constexpr float DS = 0.81873075307798185867f;  // exp(-1/5)

// ---------------- workspace layout (float units) ----------------
constexpr size_t o_wt   = 0;                                  // [3136][600] f32
constexpr size_t o_inb  = o_wt  + (size_t)3136 * 600;         // [16][128][32] u32 input row masks (pre-shifted <<2)
constexpr size_t o_p1b  = o_inb + (size_t)16 * 128 * 32;      // [16][128][32][18] u32 pooled conv1 bit rows (pre-shifted <<2)
constexpr size_t o_flag = o_p1b + (size_t)16 * 128 * 32 * 18; // [128][32] u16 per-ic activity masks
constexpr size_t o_p2m  = o_flag + 2048;                      // [128][64][49] u16 per-pos t-masks
constexpr size_t o_c1   = o_p2m + 200704;                     // [16][128][600] f32 fc1 pre-activations
constexpr size_t TOTALF = o_c1 + (size_t)16 * 128 * 600 + 16; // ~18 MB

// ---------------- helpers ----------------
__device__ __forceinline__ void block_sum_atomic(float v, float* red, float* dst) {
    int lane = threadIdx.x & 63;
    int wid  = threadIdx.x >> 6;
    #pragma unroll
    for (int o = 32; o; o >>= 1) v += __shfl_down(v, o, 64);
    if (lane == 0) red[wid] = v;
    __syncthreads();
    if (threadIdx.x == 0) {
        int nw = ((int)blockDim.x + 63) >> 6;
        float t = 0.f;
        for (int w = 0; w < nw; ++w) t += red[w];
        if (t != 0.f) atomicAdd(dst, t);
    }
    __syncthreads();
}

// tiled transpose: w[600][3136] -> wt[3136][600]; block (0,0) also zeroes counters
__global__ void k_transpose(const float* __restrict__ w, float* __restrict__ wt,
                            float* __restrict__ outz) {
    __shared__ float tile[32][33];
    int k0 = blockIdx.x * 32, j0 = blockIdx.y * 32;
    int lx = threadIdx.x & 31, ly = threadIdx.x >> 5;
    if (blockIdx.x == 0 && blockIdx.y == 0 && threadIdx.x < 5) outz[threadIdx.x] = 0.f;
    #pragma unroll
    for (int r = 0; r < 32; r += 8) {
        int j = j0 + ly + r, k = k0 + lx;
        tile[ly + r][lx] = (j < 600 && k < 3136) ? w[(size_t)j * 3136 + k] : 0.f;
    }
    __syncthreads();
    #pragma unroll
    for (int r = 0; r < 32; r += 8) {
        int k = k0 + ly + r, j = j0 + lx;
        if (k < 3136 && j < 600) wt[(size_t)k * 600 + j] = tile[lx][ly + r];
    }
}

// ---------------- input encoding -> bit rows (stored pre-shifted by 2) ----------------
__launch_bounds__(896)
__global__ void k_encode(const float* __restrict__ inp, unsigned* __restrict__ inb,
                         float* __restrict__ ssp) {
    __shared__ float red[16];
    int b = blockIdx.x, tid = threadIdx.x;
    int w = tid >> 6, lane = tid & 63;
    int r = lane >> 5, x = lane & 31;
    int y = 2 * w + r;
    float xv = (x < 28) ? inp[b * 784 + y * 28 + x] * 0.3f : 0.f;
    if (tid < 64) {
        int t = tid >> 2, rsel = tid & 3;
        inb[((size_t)t * 128 + b) * 32 + (rsel < 2 ? rsel : 28 + rsel)] = 0u;
    }
    float uin = 0.f, isp = 0.f, cnt = 0.f;
    for (int t = 0; t < 16; ++t) {
        uin = uin * DM * (1.f - isp) + xv;
        isp = (uin > 1.f && x < 28) ? 1.f : 0.f;
        cnt += isp;
        unsigned long long m = __ballot(isp != 0.f);
        if (lane == 0)       inb[((size_t)t * 128 + b) * 32 + (2 * w + 2)] = ((unsigned)m) << 2;
        else if (lane == 32) inb[((size_t)t * 128 + b) * 32 + (2 * w + 3)] = ((unsigned)(m >> 32)) << 2;
    }
    block_sum_atomic(cnt, red, &ssp[0]);
}

// ---------------- conv1: split float2 LUTs (conflict fix), t0-skip, spike-gated pool --
// block = (b, oc-pair); thread = one 2x2 pool window -> 4 neurons x 2 oc in registers
__launch_bounds__(256)
__global__ void k_conv1(const float* __restrict__ w1, const unsigned* __restrict__ inb,
                        unsigned* __restrict__ p1b, unsigned short* __restrict__ flags,
                        float* __restrict__ ssp) {
    __shared__ float2 lutA[320];      // [ky][64] {A_cc0, A_cc1} — b64 reads: ~4-way max alias
    __shared__ float2 lutB[320];      // [ky][64] {B_cc0, B_cc1}
    __shared__ unsigned sib[512];     // [16][32] pre-shifted input bit rows for this b
    __shared__ unsigned wor[8];
    __shared__ unsigned s_tm[4];      // per-wave input-activity t-masks
    __shared__ float red[4];
    int bo = blockIdx.x, b = bo >> 4, op = bo & 15;
    int oc0 = op * 2;
    int tid = threadIdx.x;
    int px = tid & 15, py = tid >> 4;
    bool pv = (px < 14) && (py < 14);
    int pb = (py < 14) ? 2 * py : 0;

    if (tid < 128) {                  // zero pad rows of both oc planes, all t
        int t = tid >> 3, k = tid & 7;
        int oc = oc0 + (k >> 2), rsel = k & 3;
        p1b[(((size_t)t * 128 + b) * 32 + oc) * 18 + (rsel < 2 ? rsel : 14 + rsel)] = 0u;
    }
    for (int e = tid; e < 320; e += 256) {
        int ky = e >> 6, m = e & 63;
        const float* wA = w1 + oc0 * 25 + ky * 5;
        float a0 = 0.f, a1 = 0.f, b0 = 0.f, b1 = 0.f;
        #pragma unroll
        for (int kx = 0; kx < 5; ++kx) {
            if ((m >> kx) & 1)       { a0 += wA[kx]; b0 += wA[25 + kx]; }
            if ((m >> (kx + 1)) & 1) { a1 += wA[kx]; b1 += wA[25 + kx]; }
        }
        lutA[e] = make_float2(a0, a1);
        lutB[e] = make_float2(b0, b1);
    }
    // load input rows + accumulate per-t activity bits (wave-local OR)
    unsigned lb = 0;
    {
        unsigned w0 = inb[((size_t)(tid >> 5) * 128 + b) * 32 + (tid & 31)];
        unsigned w1v = inb[((size_t)((tid + 256) >> 5) * 128 + b) * 32 + (tid & 31)];
        sib[tid] = w0;
        sib[tid + 256] = w1v;
        if (w0)  lb |= 1u << (tid >> 5);
        if (w1v) lb |= 1u << ((tid >> 5) + 8);
    }
    #pragma unroll
    for (int off = 32; off; off >>= 1) lb |= __shfl_xor(lb, off, 64);
    if ((tid & 63) == 0) s_tm[tid >> 6] = lb;
    if (tid < 8) wor[tid] = 0u;
    __syncthreads();

    unsigned tmask = s_tm[0] | s_tm[1] | s_tm[2] | s_tm[3];
    unsigned smask = tmask;           // prefix-or: bit t set if any input spike at t' <= t
    smask |= smask << 1; smask |= smask << 2; smask |= smask << 4; smask |= smask << 8;

    float umA[2][2] = {}, usA[2][2] = {}, teA[2][2] = {};
    float savA[2][2] = {{1.f,1.f},{1.f,1.f}}, ltA[2][2] = {{16.f,16.f},{16.f,16.f}};
    float umB[2][2] = {}, usB[2][2] = {}, teB[2][2] = {};
    float savB[2][2] = {{1.f,1.f},{1.f,1.f}}, ltB[2][2] = {{16.f,16.f},{16.f,16.f}};
    unsigned pmA = 0, pmB = 0;

    for (int t = 0; t < 16; ++t) {
        if (!((smask >> t) & 1u)) continue;   // block-uniform: no input anywhere yet
        unsigned rw[6];
        #pragma unroll
        for (int j = 0; j < 6; ++j) rw[j] = sib[t * 32 + pb + j];
        unsigned orall = rw[0] | rw[1] | rw[2] | rw[3] | rw[4] | rw[5];

        float cA[2][2] = {}, cB[2][2] = {};
        if (orall) {
            unsigned sh[6];
            #pragma unroll
            for (int j = 0; j < 6; ++j) sh[j] = (rw[j] >> (2 * px)) & 63u;
            #pragma unroll
            for (int r = 0; r < 2; ++r)
                #pragma unroll
                for (int ky = 0; ky < 5; ++ky) {
                    unsigned idx = ky * 64 + sh[r + ky];
                    float2 vA = lutA[idx];
                    float2 vB = lutB[idx];
                    cA[r][0] += vA.x; cA[r][1] += vA.y;
                    cB[r][0] += vB.x; cB[r][1] += vB.y;
                }
        }
        float sA[2][2], sB[2][2];
        #pragma unroll
        for (int r = 0; r < 2; ++r)
            #pragma unroll
            for (int cc = 0; cc < 2; ++cc) {
                umA[r][cc] = fmaf(umA[r][cc], DM, cA[r][cc]);
                usA[r][cc] = fmaf(usA[r][cc], DS, cA[r][cc]);
                float uA = savA[r][cc] * (umA[r][cc] - usA[r][cc]);
                bool fA = uA > 1.f;
                float a = fA ? 1.f : 0.f;
                savA[r][cc] = fA ? 0.f : savA[r][cc];
                teA[r][cc] += ((teA[r][cc] != 0.f) || (umA[r][cc] != 0.f)) ? 1.f : 0.f;
                ltA[r][cc] += a * (teA[r][cc] - 15.f);
                sA[r][cc] = a;
                umB[r][cc] = fmaf(umB[r][cc], DM, cB[r][cc]);
                usB[r][cc] = fmaf(usB[r][cc], DS, cB[r][cc]);
                float uB = savB[r][cc] * (umB[r][cc] - usB[r][cc]);
                bool fB = uB > 1.f;
                float bb = fB ? 1.f : 0.f;
                savB[r][cc] = fB ? 0.f : savB[r][cc];
                teB[r][cc] += ((teB[r][cc] != 0.f) || (umB[r][cc] != 0.f)) ? 1.f : 0.f;
                ltB[r][cc] += bb * (teB[r][cc] - 15.f);
                sB[r][cc] = bb;
            }
        // spike-gated tail: p1b rows for (t,b,oc) are only read by conv2 when the
        // flag bit t is set, which requires a spike here -> nothing to do otherwise
        float sany = sA[0][0] + sA[0][1] + sA[1][0] + sA[1][1]
                   + sB[0][0] + sB[0][1] + sB[1][0] + sB[1][1];
        if (!__any(pv && sany != 0.f)) continue;
        float lmA = fminf(fminf(ltA[0][0], ltA[0][1]), fminf(ltA[1][0], ltA[1][1]));
        float oA = fmaxf(fmaxf(ltA[0][0] == lmA ? sA[0][0] : 0.f, ltA[0][1] == lmA ? sA[0][1] : 0.f),
                         fmaxf(ltA[1][0] == lmA ? sA[1][0] : 0.f, ltA[1][1] == lmA ? sA[1][1] : 0.f));
        float lmB = fminf(fminf(ltB[0][0], ltB[0][1]), fminf(ltB[1][0], ltB[1][1]));
        float oB = fmaxf(fmaxf(ltB[0][0] == lmB ? sB[0][0] : 0.f, ltB[0][1] == lmB ? sB[0][1] : 0.f),
                         fmaxf(ltB[1][0] == lmB ? sB[1][0] : 0.f, ltB[1][1] == lmB ? sB[1][1] : 0.f));
        bool hitA = (oA != 0.f) && pv;
        bool hitB = (oB != 0.f) && pv;
        unsigned long long balA = __ballot(hitA);
        unsigned long long balB = __ballot(hitB);
        int k = tid & 63;
        if (k < 4) {
            int prow = (tid >> 6) * 4 + k;
            if (prow < 14) {
                unsigned wdA = ((unsigned)(balA >> (k * 16)) & 0x3FFFu) << 2;  // pre-shift for conv2
                unsigned wdB = ((unsigned)(balB >> (k * 16)) & 0x3FFFu) << 2;
                p1b[(((size_t)t * 128 + b) * 32 + oc0)     * 18 + prow + 2] = wdA;
                p1b[(((size_t)t * 128 + b) * 32 + oc0 + 1) * 18 + prow + 2] = wdB;
            }
        }
        if (hitA) pmA |= 1u << t;
        if (hitB) pmB |= 1u << t;
    }

    unsigned pA = pmA, pB = pmB;
    #pragma unroll
    for (int off = 32; off; off >>= 1) {
        pA |= __shfl_xor(pA, off, 64);
        pB |= __shfl_xor(pB, off, 64);
    }
    if ((tid & 63) == 0) { wor[(tid >> 6) * 2] = pA; wor[(tid >> 6) * 2 + 1] = pB; }
    // spike count = spiked neurons = 8 - surviving sav (each neuron fires <= once)
    float cnt = 0.f;
    if (pv)
        cnt = 8.f - (savA[0][0] + savA[0][1] + savA[1][0] + savA[1][1]
                   + savB[0][0] + savB[0][1] + savB[1][0] + savB[1][1]);
    block_sum_atomic(cnt, red, &ssp[1]);   // barriers inside make wor visible
    if (tid == 0) {
        flags[b * 32 + oc0]     = (unsigned short)(wor[0] | wor[2] | wor[4] | wor[6]);
        flags[b * 32 + oc0 + 1] = (unsigned short)(wor[1] | wor[3] | wor[5] | wor[7]);
    }
}

// ---------------- conv2: bit-LUT, oc-paired, spike-gated pool, started-skip ------
// block = (b-quad, oc-pair); wave = one b; thread = 2x2 pool window x 2 oc
__launch_bounds__(256)
__global__ void k_conv2(const float* __restrict__ w2, const unsigned* __restrict__ p1b,
                        const unsigned short* __restrict__ flags,
                        unsigned short* __restrict__ p2m, float* __restrict__ ssp) {
    __shared__ float2 lut2[5120];     // [ic*5+ky][32] x {ocA, ocB} = 40960 B exactly
    int bo = blockIdx.x, op = bo & 31, bq = bo >> 5;
    int oc0 = op * 2;
    int tid = threadIdx.x;
    int wv = tid >> 6, lane = tid & 63;
    int b = bq * 4 + wv;
    bool valid = lane < 49;
    int pr = valid ? (lane / 7) : 0;
    int pc = valid ? (lane - pr * 7) : 0;
    int y0 = 2 * pr, x0 = 2 * pc;

    for (int e = tid; e < 5120; e += 256) {
        int m = e & 31, icky = e >> 5;
        const float* wA = w2 + oc0 * 800 + icky * 5;
        float a = 0.f, c = 0.f;
        #pragma unroll
        for (int kx = 0; kx < 5; ++kx)
            if ((m >> kx) & 1) { a += wA[kx]; c += wA[800 + kx]; }
        lut2[e] = make_float2(a, c);
    }
    unsigned fl = flags[b * 32 + (lane & 31)];
    __syncthreads();

    float umA[2][2] = {}, usA[2][2] = {}, teA[2][2] = {};
    float savA[2][2] = {{1.f,1.f},{1.f,1.f}}, ltA[2][2] = {{16.f,16.f},{16.f,16.f}};
    float umB[2][2] = {}, usB[2][2] = {}, teB[2][2] = {};
    float savB[2][2] = {{1.f,1.f},{1.f,1.f}}, ltB[2][2] = {{16.f,16.f},{16.f,16.f}};
    unsigned pmA = 0, pmB = 0;
    bool started = false;

    for (int t = 0; t < 16; ++t) {
        unsigned actbm = (unsigned)__ballot(((fl >> t) & 1u) && (lane < 32));
        started = started || (actbm != 0);
        if (!started) continue;       // wave-uniform: no input ever -> no-op step
        float cA[2][2] = {}, cB[2][2] = {};
        unsigned bm = actbm;
        while (bm) {
            int ic = __builtin_ctz(bm); bm &= bm - 1;
            const unsigned* rp = p1b + (((size_t)t * 128 + b) * 32 + ic) * 18 + y0;
            unsigned r0 = rp[0], r1 = rp[1], r2 = rp[2],
                     r3 = rp[3], r4 = rp[4], r5 = rp[5];   // pre-shifted by conv1
            unsigned orall = r0 | r1 | r2 | r3 | r4 | r5;
            if (!valid || ((orall >> x0) & 63u) == 0) continue;
            unsigned sh[6] = {r0 >> x0, r1 >> x0, r2 >> x0, r3 >> x0, r4 >> x0, r5 >> x0};
            int base = ic * 160;
            #pragma unroll
            for (int r = 0; r < 2; ++r)
                #pragma unroll
                for (int ky = 0; ky < 5; ++ky) {
                    unsigned s6 = sh[r + ky];
                    float2 v0 = lut2[base + ky * 32 + (s6 & 31u)];
                    float2 v1 = lut2[base + ky * 32 + ((s6 >> 1) & 31u)];
                    cA[r][0] += v0.x; cB[r][0] += v0.y;
                    cA[r][1] += v1.x; cB[r][1] += v1.y;
                }
        }
        float sA[2][2], sB[2][2];
        #pragma unroll
        for (int r = 0; r < 2; ++r)
            #pragma unroll
            for (int cc = 0; cc < 2; ++cc) {
                umA[r][cc] = fmaf(umA[r][cc], DM, cA[r][cc]);
                usA[r][cc] = fmaf(usA[r][cc], DS, cA[r][cc]);
                float uA = savA[r][cc] * (umA[r][cc] - usA[r][cc]);
                bool fA = uA > 1.f;
                float a = fA ? 1.f : 0.f;
                savA[r][cc] = fA ? 0.f : savA[r][cc];
                teA[r][cc] += ((teA[r][cc] != 0.f) || (umA[r][cc] != 0.f)) ? 1.f : 0.f;
                ltA[r][cc] += a * (teA[r][cc] - 15.f);
                sA[r][cc] = a;
                umB[r][cc] = fmaf(umB[r][cc], DM, cB[r][cc]);
                usB[r][cc] = fmaf(usB[r][cc], DS, cB[r][cc]);
                float uB = savB[r][cc] * (umB[r][cc] - usB[r][cc]);
                bool fB = uB > 1.f;
                float bb = fB ? 1.f : 0.f;
                savB[r][cc] = fB ? 0.f : savB[r][cc];
                teB[r][cc] += ((teB[r][cc] != 0.f) || (umB[r][cc] != 0.f)) ? 1.f : 0.f;
                ltB[r][cc] += bb * (teB[r][cc] - 15.f);
                sB[r][cc] = bb;
            }
        float sany = sA[0][0] + sA[0][1] + sA[1][0] + sA[1][1]
                   + sB[0][0] + sB[0][1] + sB[1][0] + sB[1][1];
        if (!__any(valid && sany != 0.f)) continue;   // pm can't change w/o a spike
        float lmA = fminf(fminf(ltA[0][0], ltA[0][1]), fminf(ltA[1][0], ltA[1][1]));
        float oA = fmaxf(fmaxf(ltA[0][0] == lmA ? sA[0][0] : 0.f, ltA[0][1] == lmA ? sA[0][1] : 0.f),
                         fmaxf(ltA[1][0] == lmA ? sA[1][0] : 0.f, ltA[1][1] == lmA ? sA[1][1] : 0.f));
        float lmB = fminf(fminf(ltB[0][0], ltB[0][1]), fminf(ltB[1][0], ltB[1][1]));
        float oB = fmaxf(fmaxf(ltB[0][0] == lmB ? sB[0][0] : 0.f, ltB[0][1] == lmB ? sB[0][1] : 0.f),
                         fmaxf(ltB[1][0] == lmB ? sB[1][0] : 0.f, ltB[1][1] == lmB ? sB[1][1] : 0.f));
        if (valid && oA != 0.f) pmA |= 1u << t;
        if (valid && oB != 0.f) pmB |= 1u << t;
    }
    if (valid) {
        int pos = pr * 7 + pc;
        p2m[((size_t)b * 64 + oc0)     * 49 + pos] = (unsigned short)pmA;
        p2m[((size_t)b * 64 + oc0 + 1) * 49 + pos] = (unsigned short)pmB;
    }
    float cnt = 0.f;
    if (valid)
        cnt = 8.f - (savA[0][0] + savA[0][1] + savA[1][0] + savA[1][1]
                   + savB[0][0] + savB[0][1] + savB[1][0] + savB[1][1]);
    __syncthreads();                  // done with lut2 -> reuse as reduction scratch
    block_sum_atomic(cnt, (float*)lut2, &ssp[2]);
}

// ---------------- fc1 pre-activations: one block per (t,b), fully parallel ----------------
__launch_bounds__(640)
__global__ void k_fc1pre(const float* __restrict__ wt, const unsigned short* __restrict__ p2m,
                         float* __restrict__ C1) {
    __shared__ unsigned short s_m[3136];
    __shared__ int s_idx[3136];
    __shared__ int s_nnz;
    int bt = blockIdx.x;              // t*128 + b
    int b = bt & 127, t = bt >> 7;
    int tid = threadIdx.x;

    for (int k = tid; k < 3136; k += 640) s_m[k] = p2m[(size_t)b * 3136 + k];
    __syncthreads();
    if (tid < 64) {
        int count = 0;
        for (int o = 0; o < 64; ++o) {   // ascending (oc, pos): deterministic
            unsigned v = (tid < 49) ? (unsigned)s_m[o * 49 + tid] : 0u;
            unsigned long long m = __ballot((v >> t) & 1u);
            if ((m >> tid) & 1ull)
                s_idx[count + __popcll(m & ((1ull << tid) - 1ull))] = o * 49 + tid;
            count += __popcll(m);
        }
        if (tid == 0) s_nnz = count;
    }
    __syncthreads();
    int nnz = s_nnz;

    if (tid < 600) {
        float a0 = 0.f, a1 = 0.f, a2 = 0.f, a3 = 0.f;
        int i = 0;
        for (; i + 4 <= nnz; i += 4) {
            a0 += wt[(size_t)s_idx[i]     * 600 + tid];
            a1 += wt[(size_t)s_idx[i + 1] * 600 + tid];
            a2 += wt[(size_t)s_idx[i + 2] * 600 + tid];
            a3 += wt[(size_t)s_idx[i + 3] * 600 + tid];
        }
        for (; i < nnz; ++i) a0 += wt[(size_t)s_idx[i] * 600 + tid];
        C1[(size_t)bt * 600 + tid] = (a0 + a1) + (a2 + a3);
    }
}

// ---------------- fc1 recurrence + fc2: registers only ----------------
__launch_bounds__(640)
__global__ void k_fc12b(const float* __restrict__ C1, const float* __restrict__ wf2,
                        float* __restrict__ out) {
    __shared__ unsigned short s_m1[600];
    __shared__ float red[16];
    __shared__ float s_c2[10];
    int b = blockIdx.x, tid = threadIdx.x;
    int w = tid >> 6, lane = tid & 63;

    float cnt1 = 0.f;
    if (tid < 600) {
        float c[16];
        #pragma unroll
        for (int t = 0; t < 16; ++t) c[t] = C1[((size_t)t * 128 + b) * 600 + tid];
        float um = 0.f, us = 0.f, sv = 1.f;
        unsigned msk = 0;
        #pragma unroll
        for (int t = 0; t < 16; ++t) {
            um = fmaf(um, DM, c[t]);
            us = fmaf(us, DS, c[t]);
            float u = sv * (um - us);
            float s = (u > 1.f) ? 1.f : 0.f;
            sv *= (1.f - s);
            msk |= (s != 0.f) ? (1u << t) : 0u;
            cnt1 += s;
        }
        s_m1[tid] = (unsigned short)msk;
    }
    block_sum_atomic(cnt1, red, &out[2563]);   // barriers inside: s_m1 now visible

    const float* wrow = wf2 + w * 600;
    float wv[10]; unsigned mv[10];
    #pragma unroll
    for (int i = 0; i < 10; ++i) {
        int j = lane + i * 64;
        bool ok = (j < 600);
        wv[i] = ok ? wrow[j] : 0.f;
        mv[i] = ok ? (unsigned)s_m1[j] : 0u;
    }
    float f2um = 0.f, f2us = 0.f, f2sv = 1.f;
    float tel = 0.f, ot = 16.f, ou = 0.f, cnt2 = 0.f;
    for (int t = 0; t < 16; ++t) {
        float a = 0.f;
        #pragma unroll
        for (int i = 0; i < 10; ++i) a += ((mv[i] >> t) & 1u) ? wv[i] : 0.f;
        #pragma unroll
        for (int o = 32; o; o >>= 1) a += __shfl_down(a, o, 64);
        if (lane == 0) {
            f2um = fmaf(f2um, DM, a);
            f2us = fmaf(f2us, DS, a);
            float u = f2sv * (f2um - f2us);
            float s2 = (u > 1.f) ? 1.f : 0.f;
            f2sv *= (1.f - s2);
            tel += ((tel != 0.f) || (u != 0.f)) ? 1.f : 0.f;
            ot += s2 * (tel - 16.f);
            ou += s2 * u;
            cnt2 += s2;
        }
    }
    if (lane == 0) {
        out[b * 10 + w] = ot;
        out[1280 + b * 10 + w] = ou;
        s_c2[w] = cnt2;
    }
    __syncthreads();
    if (tid == 0) {
        float tt = 0.f;
        for (int j = 0; j < 10; ++j) tt += s_c2[j];
        if (tt != 0.f) atomicAdd(&out[2564], tt);
    }
}

// ---------------- launch ----------------
extern "C" void kernel_launch(void* const* d_in, const int* in_sizes, int n_in,
                              void* d_out, int out_size, void* d_ws, size_t ws_size,
                              hipStream_t stream) {
    (void)in_sizes; (void)n_in; (void)out_size;
    if (ws_size < TOTALF * sizeof(float)) return;  // ~18 MB

    const float* inp = (const float*)d_in[0];
    const float* w1  = (const float*)d_in[1];
    const float* w2  = (const float*)d_in[2];
    const float* wf1 = (const float*)d_in[3];
    const float* wf2 = (const float*)d_in[4];
    float* ws  = (float*)d_ws;
    float* out = (float*)d_out;

    // transpose also zeroes out[2560..2564] (block 0,0) before any counter atomics
    k_transpose<<<dim3(98, 19), 256, 0, stream>>>(wf1, ws + o_wt, out + 2560);

    k_encode<<<BATCH, 896, 0, stream>>>(inp, (unsigned*)(ws + o_inb), out + 2560);
    k_conv1<<<BATCH * 16, 256, 0, stream>>>(w1, (const unsigned*)(ws + o_inb),
                                            (unsigned*)(ws + o_p1b),
                                            (unsigned short*)(ws + o_flag), out + 2560);
    k_conv2<<<(BATCH / 4) * 32, 256, 0, stream>>>(w2, (const unsigned*)(ws + o_p1b),
                                                  (const unsigned short*)(ws + o_flag),
                                                  (unsigned short*)(ws + o_p2m), out + 2560);
    k_fc1pre<<<16 * BATCH, 640, 0, stream>>>(ws + o_wt, (const unsigned short*)(ws + o_p2m),
                                             ws + o_c1);
    k_fc12b<<<BATCH, 640, 0, stream>>>(ws + o_c1, wf2, out);
}

// Round 14
// 99.279 us; speedup vs baseline: 1.0727x; 1.0727x over previous
//
#include <hip/hip_runtime.h>

#define BATCH 128

constexpr float DM = 0.95122942450071400910f;  // exp(-1/20)
constexpr float DS = 0.81873075307798185867f;  // exp(-1/5)

// ---------------- workspace layout (float units) ----------------
constexpr size_t o_wt   = 0;                                  // [3136][600] f32
constexpr size_t o_inb  = o_wt  + (size_t)3136 * 600;         // [16][128][32] u32 input row masks (pre-shifted <<2)
constexpr size_t o_p1b  = o_inb + (size_t)16 * 128 * 32;      // [16][128][32][18] u32 pooled conv1 bit rows (pre-shifted <<2)
constexpr size_t o_flag = o_p1b + (size_t)16 * 128 * 32 * 18; // [128][32] u16 per-ic activity masks
constexpr size_t o_p2m  = o_flag + 2048;                      // [128][64][49] u16 per-pos t-masks
constexpr size_t o_c1   = o_p2m + 200704;                     // [16][128][600] f32 fc1 pre-activations
constexpr size_t TOTALF = o_c1 + (size_t)16 * 128 * 600 + 16; // ~18 MB

// ---------------- helpers ----------------
__device__ __forceinline__ void block_sum_atomic(float v, float* red, float* dst) {
    int lane = threadIdx.x & 63;
    int wid  = threadIdx.x >> 6;
    #pragma unroll
    for (int o = 32; o; o >>= 1) v += __shfl_down(v, o, 64);
    if (lane == 0) red[wid] = v;
    __syncthreads();
    if (threadIdx.x == 0) {
        int nw = ((int)blockDim.x + 63) >> 6;
        float t = 0.f;
        for (int w = 0; w < nw; ++w) t += red[w];
        if (t != 0.f) atomicAdd(dst, t);
    }
    __syncthreads();
}

// tiled transpose: w[600][3136] -> wt[3136][600]; block (0,0) also zeroes counters
__global__ void k_transpose(const float* __restrict__ w, float* __restrict__ wt,
                            float* __restrict__ outz) {
    __shared__ float tile[32][33];
    int k0 = blockIdx.x * 32, j0 = blockIdx.y * 32;
    int lx = threadIdx.x & 31, ly = threadIdx.x >> 5;
    if (blockIdx.x == 0 && blockIdx.y == 0 && threadIdx.x < 5) outz[threadIdx.x] = 0.f;
    #pragma unroll
    for (int r = 0; r < 32; r += 8) {
        int j = j0 + ly + r, k = k0 + lx;
        tile[ly + r][lx] = (j < 600 && k < 3136) ? w[(size_t)j * 3136 + k] : 0.f;
    }
    __syncthreads();
    #pragma unroll
    for (int r = 0; r < 32; r += 8) {
        int k = k0 + ly + r, j = j0 + lx;
        if (k < 3136 && j < 600) wt[(size_t)k * 600 + j] = tile[lx][ly + r];
    }
}

// ---------------- input encoding -> bit rows (stored pre-shifted by 2) ----------------
__launch_bounds__(896)
__global__ void k_encode(const float* __restrict__ inp, unsigned* __restrict__ inb,
                         float* __restrict__ ssp) {
    __shared__ float red[16];
    int b = blockIdx.x, tid = threadIdx.x;
    int w = tid >> 6, lane = tid & 63;
    int r = lane >> 5, x = lane & 31;
    int y = 2 * w + r;
    float xv = (x < 28) ? inp[b * 784 + y * 28 + x] * 0.3f : 0.f;
    if (tid < 64) {
        int t = tid >> 2, rsel = tid & 3;
        inb[((size_t)t * 128 + b) * 32 + (rsel < 2 ? rsel : 28 + rsel)] = 0u;
    }
    float uin = 0.f, isp = 0.f, cnt = 0.f;
    for (int t = 0; t < 16; ++t) {
        uin = uin * DM * (1.f - isp) + xv;
        isp = (uin > 1.f && x < 28) ? 1.f : 0.f;
        cnt += isp;
        unsigned long long m = __ballot(isp != 0.f);
        if (lane == 0)       inb[((size_t)t * 128 + b) * 32 + (2 * w + 2)] = ((unsigned)m) << 2;
        else if (lane == 32) inb[((size_t)t * 128 + b) * 32 + (2 * w + 3)] = ((unsigned)(m >> 32)) << 2;
    }
    block_sum_atomic(cnt, red, &ssp[0]);
}

// ---------------- conv1: float4 LUT x2 bank-offset copies, t0-skip, spike-gated pool --
// block = (b, oc-pair); thread = one 2x2 pool window -> 4 neurons x 2 oc in registers
__launch_bounds__(256)
__global__ void k_conv1(const float* __restrict__ w1, const unsigned* __restrict__ inb,
                        unsigned* __restrict__ p1b, unsigned short* __restrict__ flags,
                        float* __restrict__ ssp) {
    __shared__ float4 lutbuf[641];    // copy0 @ [0..319], copy1 @ [321..640] (+5136 B = bank shift 4)
    __shared__ unsigned sib[512];     // [16][32] pre-shifted input bit rows for this b
    __shared__ unsigned wor[8];
    __shared__ unsigned s_tm[4];      // per-wave input-activity t-masks
    __shared__ float red[4];
    int bo = blockIdx.x, b = bo >> 4, op = bo & 15;
    int oc0 = op * 2;
    int tid = threadIdx.x;
    int px = tid & 15, py = tid >> 4;
    bool pv = (px < 14) && (py < 14);
    int pb = (py < 14) ? 2 * py : 0;

    if (tid < 128) {                  // zero pad rows of both oc planes, all t
        int t = tid >> 3, k = tid & 7;
        int oc = oc0 + (k >> 2), rsel = k & 3;
        p1b[(((size_t)t * 128 + b) * 32 + oc) * 18 + (rsel < 2 ? rsel : 14 + rsel)] = 0u;
    }
    for (int e = tid; e < 320; e += 256) {
        int ky = e >> 6, m = e & 63;
        const float* wA = w1 + oc0 * 25 + ky * 5;
        float a0 = 0.f, a1 = 0.f, b0 = 0.f, b1 = 0.f;
        #pragma unroll
        for (int kx = 0; kx < 5; ++kx) {
            if ((m >> kx) & 1)       { a0 += wA[kx]; b0 += wA[25 + kx]; }
            if ((m >> (kx + 1)) & 1) { a1 += wA[kx]; b1 += wA[25 + kx]; }
        }
        float4 v = make_float4(a0, a1, b0, b1);
        lutbuf[e] = v;
        lutbuf[321 + e] = v;          // bank-offset replica
    }
    // odd lanes use the +4-bank replica: random-gather collisions split across copies
    const float4* myl = lutbuf + ((tid & 1) ? 321 : 0);
    // load input rows + accumulate per-t activity bits (wave-local OR)
    unsigned lb = 0;
    {
        unsigned w0 = inb[((size_t)(tid >> 5) * 128 + b) * 32 + (tid & 31)];
        unsigned w1v = inb[((size_t)((tid + 256) >> 5) * 128 + b) * 32 + (tid & 31)];
        sib[tid] = w0;
        sib[tid + 256] = w1v;
        if (w0)  lb |= 1u << (tid >> 5);
        if (w1v) lb |= 1u << ((tid >> 5) + 8);
    }
    #pragma unroll
    for (int off = 32; off; off >>= 1) lb |= __shfl_xor(lb, off, 64);
    if ((tid & 63) == 0) s_tm[tid >> 6] = lb;
    if (tid < 8) wor[tid] = 0u;
    __syncthreads();

    unsigned tmask = s_tm[0] | s_tm[1] | s_tm[2] | s_tm[3];
    unsigned smask = tmask;           // prefix-or: bit t set if any input spike at t' <= t
    smask |= smask << 1; smask |= smask << 2; smask |= smask << 4; smask |= smask << 8;

    float umA[2][2] = {}, usA[2][2] = {}, teA[2][2] = {};
    float savA[2][2] = {{1.f,1.f},{1.f,1.f}}, ltA[2][2] = {{16.f,16.f},{16.f,16.f}};
    float umB[2][2] = {}, usB[2][2] = {}, teB[2][2] = {};
    float savB[2][2] = {{1.f,1.f},{1.f,1.f}}, ltB[2][2] = {{16.f,16.f},{16.f,16.f}};
    unsigned pmA = 0, pmB = 0;

    for (int t = 0; t < 16; ++t) {
        if (!((smask >> t) & 1u)) continue;   // block-uniform: no input anywhere yet
        unsigned rw[6];
        #pragma unroll
        for (int j = 0; j < 6; ++j) rw[j] = sib[t * 32 + pb + j];
        unsigned orall = rw[0] | rw[1] | rw[2] | rw[3] | rw[4] | rw[5];

        float cA[2][2] = {}, cB[2][2] = {};
        if (orall) {
            unsigned sh[6];
            #pragma unroll
            for (int j = 0; j < 6; ++j) sh[j] = (rw[j] >> (2 * px)) & 63u;
            #pragma unroll
            for (int r = 0; r < 2; ++r)
                #pragma unroll
                for (int ky = 0; ky < 5; ++ky) {
                    float4 v = myl[ky * 64 + sh[r + ky]];
                    cA[r][0] += v.x; cA[r][1] += v.y;
                    cB[r][0] += v.z; cB[r][1] += v.w;
                }
        }
        float sA[2][2], sB[2][2];
        #pragma unroll
        for (int r = 0; r < 2; ++r)
            #pragma unroll
            for (int cc = 0; cc < 2; ++cc) {
                umA[r][cc] = fmaf(umA[r][cc], DM, cA[r][cc]);
                usA[r][cc] = fmaf(usA[r][cc], DS, cA[r][cc]);
                float uA = savA[r][cc] * (umA[r][cc] - usA[r][cc]);
                bool fA = uA > 1.f;
                float a = fA ? 1.f : 0.f;
                savA[r][cc] = fA ? 0.f : savA[r][cc];
                teA[r][cc] += ((teA[r][cc] != 0.f) || (umA[r][cc] != 0.f)) ? 1.f : 0.f;
                ltA[r][cc] += a * (teA[r][cc] - 15.f);
                sA[r][cc] = a;
                umB[r][cc] = fmaf(umB[r][cc], DM, cB[r][cc]);
                usB[r][cc] = fmaf(usB[r][cc], DS, cB[r][cc]);
                float uB = savB[r][cc] * (umB[r][cc] - usB[r][cc]);
                bool fB = uB > 1.f;
                float bb = fB ? 1.f : 0.f;
                savB[r][cc] = fB ? 0.f : savB[r][cc];
                teB[r][cc] += ((teB[r][cc] != 0.f) || (umB[r][cc] != 0.f)) ? 1.f : 0.f;
                ltB[r][cc] += bb * (teB[r][cc] - 15.f);
                sB[r][cc] = bb;
            }
        // spike-gated tail: p1b rows for (t,b,oc) are only read by conv2 when the
        // flag bit t is set, which requires a spike here -> nothing to do otherwise
        float sany = sA[0][0] + sA[0][1] + sA[1][0] + sA[1][1]
                   + sB[0][0] + sB[0][1] + sB[1][0] + sB[1][1];
        if (!__any(pv && sany != 0.f)) continue;
        float lmA = fminf(fminf(ltA[0][0], ltA[0][1]), fminf(ltA[1][0], ltA[1][1]));
        float oA = fmaxf(fmaxf(ltA[0][0] == lmA ? sA[0][0] : 0.f, ltA[0][1] == lmA ? sA[0][1] : 0.f),
                         fmaxf(ltA[1][0] == lmA ? sA[1][0] : 0.f, ltA[1][1] == lmA ? sA[1][1] : 0.f));
        float lmB = fminf(fminf(ltB[0][0], ltB[0][1]), fminf(ltB[1][0], ltB[1][1]));
        float oB = fmaxf(fmaxf(ltB[0][0] == lmB ? sB[0][0] : 0.f, ltB[0][1] == lmB ? sB[0][1] : 0.f),
                         fmaxf(ltB[1][0] == lmB ? sB[1][0] : 0.f, ltB[1][1] == lmB ? sB[1][1] : 0.f));
        bool hitA = (oA != 0.f) && pv;
        bool hitB = (oB != 0.f) && pv;
        unsigned long long balA = __ballot(hitA);
        unsigned long long balB = __ballot(hitB);
        int k = tid & 63;
        if (k < 4) {
            int prow = (tid >> 6) * 4 + k;
            if (prow < 14) {
                unsigned wdA = ((unsigned)(balA >> (k * 16)) & 0x3FFFu) << 2;  // pre-shift for conv2
                unsigned wdB = ((unsigned)(balB >> (k * 16)) & 0x3FFFu) << 2;
                p1b[(((size_t)t * 128 + b) * 32 + oc0)     * 18 + prow + 2] = wdA;
                p1b[(((size_t)t * 128 + b) * 32 + oc0 + 1) * 18 + prow + 2] = wdB;
            }
        }
        if (hitA) pmA |= 1u << t;
        if (hitB) pmB |= 1u << t;
    }

    unsigned pA = pmA, pB = pmB;
    #pragma unroll
    for (int off = 32; off; off >>= 1) {
        pA |= __shfl_xor(pA, off, 64);
        pB |= __shfl_xor(pB, off, 64);
    }
    if ((tid & 63) == 0) { wor[(tid >> 6) * 2] = pA; wor[(tid >> 6) * 2 + 1] = pB; }
    // spike count = spiked neurons = 8 - surviving sav (each neuron fires <= once)
    float cnt = 0.f;
    if (pv)
        cnt = 8.f - (savA[0][0] + savA[0][1] + savA[1][0] + savA[1][1]
                   + savB[0][0] + savB[0][1] + savB[1][0] + savB[1][1]);
    block_sum_atomic(cnt, red, &ssp[1]);   // barriers inside make wor visible
    if (tid == 0) {
        flags[b * 32 + oc0]     = (unsigned short)(wor[0] | wor[2] | wor[4] | wor[6]);
        flags[b * 32 + oc0 + 1] = (unsigned short)(wor[1] | wor[3] | wor[5] | wor[7]);
    }
}

// ---------------- conv2: bit-LUT, oc-paired, spike-gated pool, started-skip ------
// block = (b-quad, oc-pair); wave = one b; thread = 2x2 pool window x 2 oc
__launch_bounds__(256)
__global__ void k_conv2(const float* __restrict__ w2, const unsigned* __restrict__ p1b,
                        const unsigned short* __restrict__ flags,
                        unsigned short* __restrict__ p2m, float* __restrict__ ssp) {
    __shared__ float2 lut2[5120];     // [ic*5+ky][32] x {ocA, ocB} = 40960 B exactly
    int bo = blockIdx.x, op = bo & 31, bq = bo >> 5;
    int oc0 = op * 2;
    int tid = threadIdx.x;
    int wv = tid >> 6, lane = tid & 63;
    int b = bq * 4 + wv;
    bool valid = lane < 49;
    int pr = valid ? (lane / 7) : 0;
    int pc = valid ? (lane - pr * 7) : 0;
    int y0 = 2 * pr, x0 = 2 * pc;

    for (int e = tid; e < 5120; e += 256) {
        int m = e & 31, icky = e >> 5;
        const float* wA = w2 + oc0 * 800 + icky * 5;
        float a = 0.f, c = 0.f;
        #pragma unroll
        for (int kx = 0; kx < 5; ++kx)
            if ((m >> kx) & 1) { a += wA[kx]; c += wA[800 + kx]; }
        lut2[e] = make_float2(a, c);
    }
    unsigned fl = flags[b * 32 + (lane & 31)];
    __syncthreads();

    float umA[2][2] = {}, usA[2][2] = {}, teA[2][2] = {};
    float savA[2][2] = {{1.f,1.f},{1.f,1.f}}, ltA[2][2] = {{16.f,16.f},{16.f,16.f}};
    float umB[2][2] = {}, usB[2][2] = {}, teB[2][2] = {};
    float savB[2][2] = {{1.f,1.f},{1.f,1.f}}, ltB[2][2] = {{16.f,16.f},{16.f,16.f}};
    unsigned pmA = 0, pmB = 0;
    bool started = false;

    for (int t = 0; t < 16; ++t) {
        unsigned actbm = (unsigned)__ballot(((fl >> t) & 1u) && (lane < 32));
        started = started || (actbm != 0);
        if (!started) continue;       // wave-uniform: no input ever -> no-op step
        float cA[2][2] = {}, cB[2][2] = {};
        unsigned bm = actbm;
        while (bm) {
            int ic = __builtin_ctz(bm); bm &= bm - 1;
            const unsigned* rp = p1b + (((size_t)t * 128 + b) * 32 + ic) * 18 + y0;
            unsigned r0 = rp[0], r1 = rp[1], r2 = rp[2],
                     r3 = rp[3], r4 = rp[4], r5 = rp[5];   // pre-shifted by conv1
            unsigned orall = r0 | r1 | r2 | r3 | r4 | r5;
            if (!valid || ((orall >> x0) & 63u) == 0) continue;
            unsigned rr[6] = {r0, r1, r2, r3, r4, r5};
            int base = ic * 160;
            #pragma unroll
            for (int r = 0; r < 2; ++r)
                #pragma unroll
                for (int ky = 0; ky < 5; ++ky) {
                    unsigned w = rr[r + ky];
                    #pragma unroll
                    for (int cc = 0; cc < 2; ++cc) {
                        float2 v = lut2[base + ky * 32 + ((w >> (x0 + cc)) & 31u)];
                        cA[r][cc] += v.x; cB[r][cc] += v.y;
                    }
                }
        }
        float sA[2][2], sB[2][2];
        #pragma unroll
        for (int r = 0; r < 2; ++r)
            #pragma unroll
            for (int cc = 0; cc < 2; ++cc) {
                umA[r][cc] = fmaf(umA[r][cc], DM, cA[r][cc]);
                usA[r][cc] = fmaf(usA[r][cc], DS, cA[r][cc]);
                float uA = savA[r][cc] * (umA[r][cc] - usA[r][cc]);
                bool fA = uA > 1.f;
                float a = fA ? 1.f : 0.f;
                savA[r][cc] = fA ? 0.f : savA[r][cc];
                teA[r][cc] += ((teA[r][cc] != 0.f) || (umA[r][cc] != 0.f)) ? 1.f : 0.f;
                ltA[r][cc] += a * (teA[r][cc] - 15.f);
                sA[r][cc] = a;
                umB[r][cc] = fmaf(umB[r][cc], DM, cB[r][cc]);
                usB[r][cc] = fmaf(usB[r][cc], DS, cB[r][cc]);
                float uB = savB[r][cc] * (umB[r][cc] - usB[r][cc]);
                bool fB = uB > 1.f;
                float bb = fB ? 1.f : 0.f;
                savB[r][cc] = fB ? 0.f : savB[r][cc];
                teB[r][cc] += ((teB[r][cc] != 0.f) || (umB[r][cc] != 0.f)) ? 1.f : 0.f;
                ltB[r][cc] += bb * (teB[r][cc] - 15.f);
                sB[r][cc] = bb;
            }
        float sany = sA[0][0] + sA[0][1] + sA[1][0] + sA[1][1]
                   + sB[0][0] + sB[0][1] + sB[1][0] + sB[1][1];
        if (!__any(valid && sany != 0.f)) continue;   // pm can't change w/o a spike
        float lmA = fminf(fminf(ltA[0][0], ltA[0][1]), fminf(ltA[1][0], ltA[1][1]));
        float oA = fmaxf(fmaxf(ltA[0][0] == lmA ? sA[0][0] : 0.f, ltA[0][1] == lmA ? sA[0][1] : 0.f),
                         fmaxf(ltA[1][0] == lmA ? sA[1][0] : 0.f, ltA[1][1] == lmA ? sA[1][1] : 0.f));
        float lmB = fminf(fminf(ltB[0][0], ltB[0][1]), fminf(ltB[1][0], ltB[1][1]));
        float oB = fmaxf(fmaxf(ltB[0][0] == lmB ? sB[0][0] : 0.f, ltB[0][1] == lmB ? sB[0][1] : 0.f),
                         fmaxf(ltB[1][0] == lmB ? sB[1][0] : 0.f, ltB[1][1] == lmB ? sB[1][1] : 0.f));
        if (valid && oA != 0.f) pmA |= 1u << t;
        if (valid && oB != 0.f) pmB |= 1u << t;
    }
    if (valid) {
        int pos = pr * 7 + pc;
        p2m[((size_t)b * 64 + oc0)     * 49 + pos] = (unsigned short)pmA;
        p2m[((size_t)b * 64 + oc0 + 1) * 49 + pos] = (unsigned short)pmB;
    }
    float cnt = 0.f;
    if (valid)
        cnt = 8.f - (savA[0][0] + savA[0][1] + savA[1][0] + savA[1][1]
                   + savB[0][0] + savB[0][1] + savB[1][0] + savB[1][1]);
    __syncthreads();                  // done with lut2 -> reuse as reduction scratch
    block_sum_atomic(cnt, (float*)lut2, &ssp[2]);
}

// ---------------- fc1 pre-activations: one block per (t,b), fully parallel ----------------
__launch_bounds__(640)
__global__ void k_fc1pre(const float* __restrict__ wt, const unsigned short* __restrict__ p2m,
                         float* __restrict__ C1) {
    __shared__ unsigned short s_m[3136];
    __shared__ int s_idx[3136];
    __shared__ int s_nnz;
    int bt = blockIdx.x;              // t*128 + b
    int b = bt & 127, t = bt >> 7;
    int tid = threadIdx.x;

    for (int k = tid; k < 3136; k += 640) s_m[k] = p2m[(size_t)b * 3136 + k];
    __syncthreads();
    if (tid < 64) {
        int count = 0;
        for (int o = 0; o < 64; ++o) {   // ascending (oc, pos): deterministic
            unsigned v = (tid < 49) ? (unsigned)s_m[o * 49 + tid] : 0u;
            unsigned long long m = __ballot((v >> t) & 1u);
            if ((m >> tid) & 1ull)
                s_idx[count + __popcll(m & ((1ull << tid) - 1ull))] = o * 49 + tid;
            count += __popcll(m);
        }
        if (tid == 0) s_nnz = count;
    }
    __syncthreads();
    int nnz = s_nnz;

    if (tid < 600) {
        float a0 = 0.f, a1 = 0.f, a2 = 0.f, a3 = 0.f;
        int i = 0;
        for (; i + 4 <= nnz; i += 4) {
            a0 += wt[(size_t)s_idx[i]     * 600 + tid];
            a1 += wt[(size_t)s_idx[i + 1] * 600 + tid];
            a2 += wt[(size_t)s_idx[i + 2] * 600 + tid];
            a3 += wt[(size_t)s_idx[i + 3] * 600 + tid];
        }
        for (; i < nnz; ++i) a0 += wt[(size_t)s_idx[i] * 600 + tid];
        C1[(size_t)bt * 600 + tid] = (a0 + a1) + (a2 + a3);
    }
}

// ---------------- fc1 recurrence + fc2: registers only ----------------
__launch_bounds__(640)
__global__ void k_fc12b(const float* __restrict__ C1, const float* __restrict__ wf2,
                        float* __restrict__ out) {
    __shared__ unsigned short s_m1[600];
    __shared__ float red[16];
    __shared__ float s_c2[10];
    int b = blockIdx.x, tid = threadIdx.x;
    int w = tid >> 6, lane = tid & 63;

    float cnt1 = 0.f;
    if (tid < 600) {
        float c[16];
        #pragma unroll
        for (int t = 0; t < 16; ++t) c[t] = C1[((size_t)t * 128 + b) * 600 + tid];
        float um = 0.f, us = 0.f, sv = 1.f;
        unsigned msk = 0;
        #pragma unroll
        for (int t = 0; t < 16; ++t) {
            um = fmaf(um, DM, c[t]);
            us = fmaf(us, DS, c[t]);
            float u = sv * (um - us);
            float s = (u > 1.f) ? 1.f : 0.f;
            sv *= (1.f - s);
            msk |= (s != 0.f) ? (1u << t) : 0u;
            cnt1 += s;
        }
        s_m1[tid] = (unsigned short)msk;
    }
    block_sum_atomic(cnt1, red, &out[2563]);   // barriers inside: s_m1 now visible

    const float* wrow = wf2 + w * 600;
    float wv[10]; unsigned mv[10];
    #pragma unroll
    for (int i = 0; i < 10; ++i) {
        int j = lane + i * 64;
        bool ok = (j < 600);
        wv[i] = ok ? wrow[j] : 0.f;
        mv[i] = ok ? (unsigned)s_m1[j] : 0u;
    }
    float f2um = 0.f, f2us = 0.f, f2sv = 1.f;
    float tel = 0.f, ot = 16.f, ou = 0.f, cnt2 = 0.f;
    for (int t = 0; t < 16; ++t) {
        float a = 0.f;
        #pragma unroll
        for (int i = 0; i < 10; ++i) a += ((mv[i] >> t) & 1u) ? wv[i] : 0.f;
        #pragma unroll
        for (int o = 32; o; o >>= 1) a += __shfl_down(a, o, 64);
        if (lane == 0) {
            f2um = fmaf(f2um, DM, a);
            f2us = fmaf(f2us, DS, a);
            float u = f2sv * (f2um - f2us);
            float s2 = (u > 1.f) ? 1.f : 0.f;
            f2sv *= (1.f - s2);
            tel += ((tel != 0.f) || (u != 0.f)) ? 1.f : 0.f;
            ot += s2 * (tel - 16.f);
            ou += s2 * u;
            cnt2 += s2;
        }
    }
    if (lane == 0) {
        out[b * 10 + w] = ot;
        out[1280 + b * 10 + w] = ou;
        s_c2[w] = cnt2;
    }
    __syncthreads();
    if (tid == 0) {
        float tt = 0.f;
        for (int j = 0; j < 10; ++j) tt += s_c2[j];
        if (tt != 0.f) atomicAdd(&out[2564], tt);
    }
}

// ---------------- launch ----------------
extern "C" void kernel_launch(void* const* d_in, const int* in_sizes, int n_in,
                              void* d_out, int out_size, void* d_ws, size_t ws_size,
                              hipStream_t stream) {
    (void)in_sizes; (void)n_in; (void)out_size;
    if (ws_size < TOTALF * sizeof(float)) return;  // ~18 MB

    const float* inp = (const float*)d_in[0];
    const float* w1  = (const float*)d_in[1];
    const float* w2  = (const float*)d_in[2];
    const float* wf1 = (const float*)d_in[3];
    const float* wf2 = (const float*)d_in[4];
    float* ws  = (float*)d_ws;
    float* out = (float*)d_out;

    // transpose also zeroes out[2560..2564] (block 0,0) before any counter atomics
    k_transpose<<<dim3(98, 19), 256, 0, stream>>>(wf1, ws + o_wt, out + 2560);

    k_encode<<<BATCH, 896, 0, stream>>>(inp, (unsigned*)(ws + o_inb), out + 2560);
    k_conv1<<<BATCH * 16, 256, 0, stream>>>(w1, (const unsigned*)(ws + o_inb),
                                            (unsigned*)(ws + o_p1b),
                                            (unsigned short*)(ws + o_flag), out + 2560);
    k_conv2<<<(BATCH / 4) * 32, 256, 0, stream>>>(w2, (const unsigned*)(ws + o_p1b),
                                                  (const unsigned short*)(ws + o_flag),
                                                  (unsigned short*)(ws + o_p2m), out + 2560);
    k_fc1pre<<<16 * BATCH, 640, 0, stream>>>(ws + o_wt, (const unsigned short*)(ws + o_p2m),
                                             ws + o_c1);
    k_fc12b<<<BATCH, 640, 0, stream>>>(ws + o_c1, wf2, out);
}

// Round 15
// 96.868 us; speedup vs baseline: 1.0994x; 1.0249x over previous
//
#include <hip/hip_runtime.h>

#define BATCH 128

constexpr float DM = 0.95122942450071400910f;  // exp(-1/20)
constexpr float DS = 0.81873075307798185867f;  // exp(-1/5)

// ---------------- workspace layout (float units) ----------------
constexpr size_t o_wt   = 0;                                  // [3136][600] f32
constexpr size_t o_inb  = o_wt  + (size_t)3136 * 600;         // [16][128][32] u32 input row masks (pre-shifted <<2)
constexpr size_t o_p1b  = o_inb + (size_t)16 * 128 * 32;      // [16][128][32][18] u32 pooled conv1 bit rows (pre-shifted <<2)
constexpr size_t o_flag = o_p1b + (size_t)16 * 128 * 32 * 18; // [128][32] u16 per-ic activity masks
constexpr size_t o_p2m  = o_flag + 2048;                      // [128][64][49] u16 per-pos t-masks
constexpr size_t o_c1   = o_p2m + 200704;                     // [16][128][600] f32 fc1 pre-activations
constexpr size_t o_cnt  = o_c1 + (size_t)16 * 128 * 600;      // [3200] per-block count partials
constexpr size_t TOTALF = o_cnt + 3200 + 16;                  // ~18 MB

// ---------------- helpers ----------------
// block-wide sum of v -> plain store to dst by tid 0. Trailing barrier.
__device__ __forceinline__ void block_sum_store(float v, float* red, float* dst) {
    int lane = threadIdx.x & 63;
    int wid  = threadIdx.x >> 6;
    #pragma unroll
    for (int o = 32; o; o >>= 1) v += __shfl_down(v, o, 64);
    if (lane == 0) red[wid] = v;
    __syncthreads();
    if (threadIdx.x == 0) {
        int nw = ((int)blockDim.x + 63) >> 6;
        float t = 0.f;
        for (int w = 0; w < nw; ++w) t += red[w];
        *dst = t;
    }
    __syncthreads();
}

__device__ __forceinline__ void block_sum_atomic(float v, float* red, float* dst) {
    int lane = threadIdx.x & 63;
    int wid  = threadIdx.x >> 6;
    #pragma unroll
    for (int o = 32; o; o >>= 1) v += __shfl_down(v, o, 64);
    if (lane == 0) red[wid] = v;
    __syncthreads();
    if (threadIdx.x == 0) {
        int nw = ((int)blockDim.x + 63) >> 6;
        float t = 0.f;
        for (int w = 0; w < nw; ++w) t += red[w];
        if (t != 0.f) atomicAdd(dst, t);
    }
    __syncthreads();
}

// ---------------- input encoding -> bit rows (stored pre-shifted by 2) ----------------
__launch_bounds__(896)
__global__ void k_encode(const float* __restrict__ inp, unsigned* __restrict__ inb,
                         float* __restrict__ cnts) {
    __shared__ float red[16];
    int b = blockIdx.x, tid = threadIdx.x;
    int w = tid >> 6, lane = tid & 63;
    int r = lane >> 5, x = lane & 31;
    int y = 2 * w + r;
    float xv = (x < 28) ? inp[b * 784 + y * 28 + x] * 0.3f : 0.f;
    if (tid < 64) {
        int t = tid >> 2, rsel = tid & 3;
        inb[((size_t)t * 128 + b) * 32 + (rsel < 2 ? rsel : 28 + rsel)] = 0u;
    }
    float uin = 0.f, isp = 0.f, cnt = 0.f;
    for (int t = 0; t < 16; ++t) {
        uin = uin * DM * (1.f - isp) + xv;
        isp = (uin > 1.f && x < 28) ? 1.f : 0.f;
        cnt += isp;
        unsigned long long m = __ballot(isp != 0.f);
        if (lane == 0)       inb[((size_t)t * 128 + b) * 32 + (2 * w + 2)] = ((unsigned)m) << 2;
        else if (lane == 32) inb[((size_t)t * 128 + b) * 32 + (2 * w + 3)] = ((unsigned)(m >> 32)) << 2;
    }
    block_sum_store(cnt, red, &cnts[b]);
}

// ---------------- conv1 + fused wf1-transpose tail ----------
// blocks [0..2047]: (b, oc-pair) conv1; blocks [2048..3909]: transpose tiles
__launch_bounds__(256)
__global__ void k_conv1(const float* __restrict__ w1, const unsigned* __restrict__ inb,
                        unsigned* __restrict__ p1b, unsigned short* __restrict__ flags,
                        const float* __restrict__ wf1, float* __restrict__ wt,
                        float* __restrict__ cnts) {
    __shared__ float4 lutbuf[320];    // conv1 LUT / transpose tile (overlaid, 5120 B)
    __shared__ unsigned sib[512];     // [16][32] pre-shifted input bit rows for this b
    __shared__ unsigned wor[8];
    __shared__ unsigned s_tm[4];      // per-wave input-activity t-masks
    __shared__ float red[4];
    int bo = blockIdx.x;
    int tid = threadIdx.x;

    if (bo >= 2048) {                 // ---- fused transpose tile: wf1[600][3136] -> wt ----
        float* tile = (float*)lutbuf; // [32][33] = 4224 B <= 5120 B
        int bx = bo - 2048;
        int k0 = (bx % 98) * 32, j0 = (bx / 98) * 32;
        int lx = tid & 31, ly = tid >> 5;
        #pragma unroll
        for (int r = 0; r < 32; r += 8) {
            int j = j0 + ly + r, k = k0 + lx;
            tile[(ly + r) * 33 + lx] = (j < 600 && k < 3136) ? wf1[(size_t)j * 3136 + k] : 0.f;
        }
        __syncthreads();
        #pragma unroll
        for (int r = 0; r < 32; r += 8) {
            int k = k0 + ly + r, j = j0 + lx;
            if (k < 3136 && j < 600) wt[(size_t)k * 600 + j] = tile[lx * 33 + ly + r];
        }
        return;
    }

    int b = bo >> 4, op = bo & 15;
    int oc0 = op * 2;
    int px = tid & 15, py = tid >> 4;
    bool pv = (px < 14) && (py < 14);
    int pb = (py < 14) ? 2 * py : 0;

    if (tid < 128) {                  // zero pad rows of both oc planes, all t
        int t = tid >> 3, k = tid & 7;
        int oc = oc0 + (k >> 2), rsel = k & 3;
        p1b[(((size_t)t * 128 + b) * 32 + oc) * 18 + (rsel < 2 ? rsel : 14 + rsel)] = 0u;
    }
    for (int e = tid; e < 320; e += 256) {
        int ky = e >> 6, m = e & 63;
        const float* wA = w1 + oc0 * 25 + ky * 5;
        float a0 = 0.f, a1 = 0.f, b0 = 0.f, b1 = 0.f;
        #pragma unroll
        for (int kx = 0; kx < 5; ++kx) {
            if ((m >> kx) & 1)       { a0 += wA[kx]; b0 += wA[25 + kx]; }
            if ((m >> (kx + 1)) & 1) { a1 += wA[kx]; b1 += wA[25 + kx]; }
        }
        lutbuf[e] = make_float4(a0, a1, b0, b1);
    }
    // load input rows + accumulate per-t activity bits (wave-local OR)
    unsigned lb = 0;
    {
        unsigned w0 = inb[((size_t)(tid >> 5) * 128 + b) * 32 + (tid & 31)];
        unsigned w1v = inb[((size_t)((tid + 256) >> 5) * 128 + b) * 32 + (tid & 31)];
        sib[tid] = w0;
        sib[tid + 256] = w1v;
        if (w0)  lb |= 1u << (tid >> 5);
        if (w1v) lb |= 1u << ((tid >> 5) + 8);
    }
    #pragma unroll
    for (int off = 32; off; off >>= 1) lb |= __shfl_xor(lb, off, 64);
    if ((tid & 63) == 0) s_tm[tid >> 6] = lb;
    if (tid < 8) wor[tid] = 0u;
    __syncthreads();

    unsigned tmask = s_tm[0] | s_tm[1] | s_tm[2] | s_tm[3];
    unsigned smask = tmask;           // prefix-or: bit t set if any input spike at t' <= t
    smask |= smask << 1; smask |= smask << 2; smask |= smask << 4; smask |= smask << 8;

    float umA[2][2] = {}, usA[2][2] = {}, teA[2][2] = {};
    float savA[2][2] = {{1.f,1.f},{1.f,1.f}}, ltA[2][2] = {{16.f,16.f},{16.f,16.f}};
    float umB[2][2] = {}, usB[2][2] = {}, teB[2][2] = {};
    float savB[2][2] = {{1.f,1.f},{1.f,1.f}}, ltB[2][2] = {{16.f,16.f},{16.f,16.f}};
    unsigned pmA = 0, pmB = 0;

    for (int t = 0; t < 16; ++t) {
        if (!((smask >> t) & 1u)) continue;   // block-uniform: no input anywhere yet
        unsigned rw[6];
        #pragma unroll
        for (int j = 0; j < 6; ++j) rw[j] = sib[t * 32 + pb + j];
        unsigned orall = rw[0] | rw[1] | rw[2] | rw[3] | rw[4] | rw[5];

        float cA[2][2] = {}, cB[2][2] = {};
        if (orall) {
            unsigned sh[6];
            #pragma unroll
            for (int j = 0; j < 6; ++j) sh[j] = (rw[j] >> (2 * px)) & 63u;
            #pragma unroll
            for (int r = 0; r < 2; ++r)
                #pragma unroll
                for (int ky = 0; ky < 5; ++ky) {
                    float4 v = lutbuf[ky * 64 + sh[r + ky]];
                    cA[r][0] += v.x; cA[r][1] += v.y;
                    cB[r][0] += v.z; cB[r][1] += v.w;
                }
        }
        float sA[2][2], sB[2][2];
        #pragma unroll
        for (int r = 0; r < 2; ++r)
            #pragma unroll
            for (int cc = 0; cc < 2; ++cc) {
                umA[r][cc] = fmaf(umA[r][cc], DM, cA[r][cc]);
                usA[r][cc] = fmaf(usA[r][cc], DS, cA[r][cc]);
                float uA = savA[r][cc] * (umA[r][cc] - usA[r][cc]);
                bool fA = uA > 1.f;
                float a = fA ? 1.f : 0.f;
                savA[r][cc] = fA ? 0.f : savA[r][cc];
                teA[r][cc] += ((teA[r][cc] != 0.f) || (umA[r][cc] != 0.f)) ? 1.f : 0.f;
                ltA[r][cc] += a * (teA[r][cc] - 15.f);
                sA[r][cc] = a;
                umB[r][cc] = fmaf(umB[r][cc], DM, cB[r][cc]);
                usB[r][cc] = fmaf(usB[r][cc], DS, cB[r][cc]);
                float uB = savB[r][cc] * (umB[r][cc] - usB[r][cc]);
                bool fB = uB > 1.f;
                float bb = fB ? 1.f : 0.f;
                savB[r][cc] = fB ? 0.f : savB[r][cc];
                teB[r][cc] += ((teB[r][cc] != 0.f) || (umB[r][cc] != 0.f)) ? 1.f : 0.f;
                ltB[r][cc] += bb * (teB[r][cc] - 15.f);
                sB[r][cc] = bb;
            }
        // spike-gated tail: p1b rows for (t,b,oc) are only read by conv2 when the
        // flag bit t is set, which requires a spike here -> nothing to do otherwise
        float sany = sA[0][0] + sA[0][1] + sA[1][0] + sA[1][1]
                   + sB[0][0] + sB[0][1] + sB[1][0] + sB[1][1];
        if (!__any(pv && sany != 0.f)) continue;
        float lmA = fminf(fminf(ltA[0][0], ltA[0][1]), fminf(ltA[1][0], ltA[1][1]));
        float oA = fmaxf(fmaxf(ltA[0][0] == lmA ? sA[0][0] : 0.f, ltA[0][1] == lmA ? sA[0][1] : 0.f),
                         fmaxf(ltA[1][0] == lmA ? sA[1][0] : 0.f, ltA[1][1] == lmA ? sA[1][1] : 0.f));
        float lmB = fminf(fminf(ltB[0][0], ltB[0][1]), fminf(ltB[1][0], ltB[1][1]));
        float oB = fmaxf(fmaxf(ltB[0][0] == lmB ? sB[0][0] : 0.f, ltB[0][1] == lmB ? sB[0][1] : 0.f),
                         fmaxf(ltB[1][0] == lmB ? sB[1][0] : 0.f, ltB[1][1] == lmB ? sB[1][1] : 0.f));
        bool hitA = (oA != 0.f) && pv;
        bool hitB = (oB != 0.f) && pv;
        unsigned long long balA = __ballot(hitA);
        unsigned long long balB = __ballot(hitB);
        int k = tid & 63;
        if (k < 4) {
            int prow = (tid >> 6) * 4 + k;
            if (prow < 14) {
                unsigned wdA = ((unsigned)(balA >> (k * 16)) & 0x3FFFu) << 2;  // pre-shift for conv2
                unsigned wdB = ((unsigned)(balB >> (k * 16)) & 0x3FFFu) << 2;
                p1b[(((size_t)t * 128 + b) * 32 + oc0)     * 18 + prow + 2] = wdA;
                p1b[(((size_t)t * 128 + b) * 32 + oc0 + 1) * 18 + prow + 2] = wdB;
            }
        }
        if (hitA) pmA |= 1u << t;
        if (hitB) pmB |= 1u << t;
    }

    unsigned pA = pmA, pB = pmB;
    #pragma unroll
    for (int off = 32; off; off >>= 1) {
        pA |= __shfl_xor(pA, off, 64);
        pB |= __shfl_xor(pB, off, 64);
    }
    if ((tid & 63) == 0) { wor[(tid >> 6) * 2] = pA; wor[(tid >> 6) * 2 + 1] = pB; }
    // spike count = spiked neurons = 8 - surviving sav (each neuron fires <= once)
    float cnt = 0.f;
    if (pv)
        cnt = 8.f - (savA[0][0] + savA[0][1] + savA[1][0] + savA[1][1]
                   + savB[0][0] + savB[0][1] + savB[1][0] + savB[1][1]);
    block_sum_store(cnt, red, &cnts[128 + bo]);   // barriers inside make wor visible
    if (tid == 0) {
        flags[b * 32 + oc0]     = (unsigned short)(wor[0] | wor[2] | wor[4] | wor[6]);
        flags[b * 32 + oc0 + 1] = (unsigned short)(wor[1] | wor[3] | wor[5] | wor[7]);
    }
}

// ---------------- conv2: bit-LUT, oc-paired, spike-gated pool, started-skip ------
// block = (b-quad, oc-pair); wave = one b; thread = 2x2 pool window x 2 oc
__launch_bounds__(256)
__global__ void k_conv2(const float* __restrict__ w2, const unsigned* __restrict__ p1b,
                        const unsigned short* __restrict__ flags,
                        unsigned short* __restrict__ p2m, float* __restrict__ cnts) {
    __shared__ float2 lut2[5120];     // [ic*5+ky][32] x {ocA, ocB} = 40960 B exactly
    int bo = blockIdx.x, op = bo & 31, bq = bo >> 5;
    int oc0 = op * 2;
    int tid = threadIdx.x;
    int wv = tid >> 6, lane = tid & 63;
    int b = bq * 4 + wv;
    bool valid = lane < 49;
    int pr = valid ? (lane / 7) : 0;
    int pc = valid ? (lane - pr * 7) : 0;
    int y0 = 2 * pr, x0 = 2 * pc;

    for (int e = tid; e < 5120; e += 256) {
        int m = e & 31, icky = e >> 5;
        const float* wA = w2 + oc0 * 800 + icky * 5;
        float a = 0.f, c = 0.f;
        #pragma unroll
        for (int kx = 0; kx < 5; ++kx)
            if ((m >> kx) & 1) { a += wA[kx]; c += wA[800 + kx]; }
        lut2[e] = make_float2(a, c);
    }
    unsigned fl = flags[b * 32 + (lane & 31)];
    __syncthreads();

    float umA[2][2] = {}, usA[2][2] = {}, teA[2][2] = {};
    float savA[2][2] = {{1.f,1.f},{1.f,1.f}}, ltA[2][2] = {{16.f,16.f},{16.f,16.f}};
    float umB[2][2] = {}, usB[2][2] = {}, teB[2][2] = {};
    float savB[2][2] = {{1.f,1.f},{1.f,1.f}}, ltB[2][2] = {{16.f,16.f},{16.f,16.f}};
    unsigned pmA = 0, pmB = 0;
    bool started = false;

    for (int t = 0; t < 16; ++t) {
        unsigned actbm = (unsigned)__ballot(((fl >> t) & 1u) && (lane < 32));
        started = started || (actbm != 0);
        if (!started) continue;       // wave-uniform: no input ever -> no-op step
        float cA[2][2] = {}, cB[2][2] = {};
        unsigned bm = actbm;
        while (bm) {
            int ic = __builtin_ctz(bm); bm &= bm - 1;
            const unsigned* rp = p1b + (((size_t)t * 128 + b) * 32 + ic) * 18 + y0;
            unsigned r0 = rp[0], r1 = rp[1], r2 = rp[2],
                     r3 = rp[3], r4 = rp[4], r5 = rp[5];   // pre-shifted by conv1
            unsigned orall = r0 | r1 | r2 | r3 | r4 | r5;
            if (!valid || ((orall >> x0) & 63u) == 0) continue;
            unsigned sh[6] = {r0 >> x0, r1 >> x0, r2 >> x0, r3 >> x0, r4 >> x0, r5 >> x0};
            int base = ic * 160;
            #pragma unroll
            for (int r = 0; r < 2; ++r)
                #pragma unroll
                for (int ky = 0; ky < 5; ++ky) {
                    unsigned s6 = sh[r + ky];
                    float2 v0 = lut2[base + ky * 32 + (s6 & 31u)];
                    float2 v1 = lut2[base + ky * 32 + ((s6 >> 1) & 31u)];
                    cA[r][0] += v0.x; cB[r][0] += v0.y;
                    cA[r][1] += v1.x; cB[r][1] += v1.y;
                }
        }
        float sA[2][2], sB[2][2];
        #pragma unroll
        for (int r = 0; r < 2; ++r)
            #pragma unroll
            for (int cc = 0; cc < 2; ++cc) {
                umA[r][cc] = fmaf(umA[r][cc], DM, cA[r][cc]);
                usA[r][cc] = fmaf(usA[r][cc], DS, cA[r][cc]);
                float uA = savA[r][cc] * (umA[r][cc] - usA[r][cc]);
                bool fA = uA > 1.f;
                float a = fA ? 1.f : 0.f;
                savA[r][cc] = fA ? 0.f : savA[r][cc];
                teA[r][cc] += ((teA[r][cc] != 0.f) || (umA[r][cc] != 0.f)) ? 1.f : 0.f;
                ltA[r][cc] += a * (teA[r][cc] - 15.f);
                sA[r][cc] = a;
                umB[r][cc] = fmaf(umB[r][cc], DM, cB[r][cc]);
                usB[r][cc] = fmaf(usB[r][cc], DS, cB[r][cc]);
                float uB = savB[r][cc] * (umB[r][cc] - usB[r][cc]);
                bool fB = uB > 1.f;
                float bb = fB ? 1.f : 0.f;
                savB[r][cc] = fB ? 0.f : savB[r][cc];
                teB[r][cc] += ((teB[r][cc] != 0.f) || (umB[r][cc] != 0.f)) ? 1.f : 0.f;
                ltB[r][cc] += bb * (teB[r][cc] - 15.f);
                sB[r][cc] = bb;
            }
        float sany = sA[0][0] + sA[0][1] + sA[1][0] + sA[1][1]
                   + sB[0][0] + sB[0][1] + sB[1][0] + sB[1][1];
        if (!__any(valid && sany != 0.f)) continue;   // pm can't change w/o a spike
        float lmA = fminf(fminf(ltA[0][0], ltA[0][1]), fminf(ltA[1][0], ltA[1][1]));
        float oA = fmaxf(fmaxf(ltA[0][0] == lmA ? sA[0][0] : 0.f, ltA[0][1] == lmA ? sA[0][1] : 0.f),
                         fmaxf(ltA[1][0] == lmA ? sA[1][0] : 0.f, ltA[1][1] == lmA ? sA[1][1] : 0.f));
        float lmB = fminf(fminf(ltB[0][0], ltB[0][1]), fminf(ltB[1][0], ltB[1][1]));
        float oB = fmaxf(fmaxf(ltB[0][0] == lmB ? sB[0][0] : 0.f, ltB[0][1] == lmB ? sB[0][1] : 0.f),
                         fmaxf(ltB[1][0] == lmB ? sB[1][0] : 0.f, ltB[1][1] == lmB ? sB[1][1] : 0.f));
        if (valid && oA != 0.f) pmA |= 1u << t;
        if (valid && oB != 0.f) pmB |= 1u << t;
    }
    if (valid) {
        int pos = pr * 7 + pc;
        p2m[((size_t)b * 64 + oc0)     * 49 + pos] = (unsigned short)pmA;
        p2m[((size_t)b * 64 + oc0 + 1) * 49 + pos] = (unsigned short)pmB;
    }
    float cnt = 0.f;
    if (valid)
        cnt = 8.f - (savA[0][0] + savA[0][1] + savA[1][0] + savA[1][1]
                   + savB[0][0] + savB[0][1] + savB[1][0] + savB[1][1]);
    __syncthreads();                  // done with lut2 -> reuse as reduction scratch
    block_sum_store(cnt, (float*)lut2, &cnts[2176 + bo]);
}

// ---------------- fc1 pre-activations: one block per (t,b), fully parallel ----------------
__launch_bounds__(640)
__global__ void k_fc1pre(const float* __restrict__ wt, const unsigned short* __restrict__ p2m,
                         float* __restrict__ C1, float* __restrict__ out) {
    __shared__ unsigned short s_m[3136];
    __shared__ int s_idx[3136];
    __shared__ int s_nnz;
    int bt = blockIdx.x;              // t*128 + b
    int b = bt & 127, t = bt >> 7;
    int tid = threadIdx.x;
    if (bt == 0 && tid < 2) out[2563 + tid] = 0.f;   // zero fc-counter atomics' targets

    for (int k = tid; k < 3136; k += 640) s_m[k] = p2m[(size_t)b * 3136 + k];
    __syncthreads();
    if (tid < 64) {
        int count = 0;
        for (int o = 0; o < 64; ++o) {   // ascending (oc, pos): deterministic
            unsigned v = (tid < 49) ? (unsigned)s_m[o * 49 + tid] : 0u;
            unsigned long long m = __ballot((v >> t) & 1u);
            if ((m >> tid) & 1ull)
                s_idx[count + __popcll(m & ((1ull << tid) - 1ull))] = o * 49 + tid;
            count += __popcll(m);
        }
        if (tid == 0) s_nnz = count;
    }
    __syncthreads();
    int nnz = s_nnz;

    if (tid < 600) {
        float a0 = 0.f, a1 = 0.f, a2 = 0.f, a3 = 0.f;
        int i = 0;
        for (; i + 4 <= nnz; i += 4) {
            a0 += wt[(size_t)s_idx[i]     * 600 + tid];
            a1 += wt[(size_t)s_idx[i + 1] * 600 + tid];
            a2 += wt[(size_t)s_idx[i + 2] * 600 + tid];
            a3 += wt[(size_t)s_idx[i + 3] * 600 + tid];
        }
        for (; i < nnz; ++i) a0 += wt[(size_t)s_idx[i] * 600 + tid];
        C1[(size_t)bt * 600 + tid] = (a0 + a1) + (a2 + a3);
    }
}

// ---------------- fc1 recurrence + fc2 + counter finalization ----------------
__launch_bounds__(640)
__global__ void k_fc12b(const float* __restrict__ C1, const float* __restrict__ wf2,
                        const float* __restrict__ cnts, float* __restrict__ out) {
    __shared__ unsigned short s_m1[600];
    __shared__ float red[16];
    __shared__ float s_c2[10];
    int b = blockIdx.x, tid = threadIdx.x;
    int w = tid >> 6, lane = tid & 63;

    float cnt1 = 0.f;
    if (tid < 600) {
        float c[16];
        #pragma unroll
        for (int t = 0; t < 16; ++t) c[t] = C1[((size_t)t * 128 + b) * 600 + tid];
        float um = 0.f, us = 0.f, sv = 1.f;
        unsigned msk = 0;
        #pragma unroll
        for (int t = 0; t < 16; ++t) {
            um = fmaf(um, DM, c[t]);
            us = fmaf(us, DS, c[t]);
            float u = sv * (um - us);
            float s = (u > 1.f) ? 1.f : 0.f;
            sv *= (1.f - s);
            msk |= (s != 0.f) ? (1u << t) : 0u;
            cnt1 += s;
        }
        s_m1[tid] = (unsigned short)msk;
    }
    block_sum_atomic(cnt1, red, &out[2563]);   // barriers inside: s_m1 now visible

    const float* wrow = wf2 + w * 600;
    float wv[10]; unsigned mv[10];
    #pragma unroll
    for (int i = 0; i < 10; ++i) {
        int j = lane + i * 64;
        bool ok = (j < 600);
        wv[i] = ok ? wrow[j] : 0.f;
        mv[i] = ok ? (unsigned)s_m1[j] : 0u;
    }
    float f2um = 0.f, f2us = 0.f, f2sv = 1.f;
    float tel = 0.f, ot = 16.f, ou = 0.f, cnt2 = 0.f;
    for (int t = 0; t < 16; ++t) {
        float a = 0.f;
        #pragma unroll
        for (int i = 0; i < 10; ++i) a += ((mv[i] >> t) & 1u) ? wv[i] : 0.f;
        #pragma unroll
        for (int o = 32; o; o >>= 1) a += __shfl_down(a, o, 64);
        if (lane == 0) {
            f2um = fmaf(f2um, DM, a);
            f2us = fmaf(f2us, DS, a);
            float u = f2sv * (f2um - f2us);
            float s2 = (u > 1.f) ? 1.f : 0.f;
            f2sv *= (1.f - s2);
            tel += ((tel != 0.f) || (u != 0.f)) ? 1.f : 0.f;
            ot += s2 * (tel - 16.f);
            ou += s2 * u;
            cnt2 += s2;
        }
    }
    if (lane == 0) {
        out[b * 10 + w] = ot;
        out[1280 + b * 10 + w] = ou;
        s_c2[w] = cnt2;
    }
    __syncthreads();
    if (tid == 0) {
        float tt = 0.f;
        for (int j = 0; j < 10; ++j) tt += s_c2[j];
        if (tt != 0.f) atomicAdd(&out[2564], tt);
    }
    // block 0: reduce per-block counter partials -> out[2560..2562] (plain writes)
    if (b == 0) {
        float v = 0.f;
        for (int k = tid; k < 128; k += 640) v += cnts[k];
        block_sum_store(v, red, &out[2560]);
        v = 0.f;
        for (int k = tid; k < 2048; k += 640) v += cnts[128 + k];
        block_sum_store(v, red, &out[2561]);
        v = 0.f;
        for (int k = tid; k < 1024; k += 640) v += cnts[2176 + k];
        block_sum_store(v, red, &out[2562]);
    }
}

// ---------------- launch ----------------
extern "C" void kernel_launch(void* const* d_in, const int* in_sizes, int n_in,
                              void* d_out, int out_size, void* d_ws, size_t ws_size,
                              hipStream_t stream) {
    (void)in_sizes; (void)n_in; (void)out_size;
    if (ws_size < TOTALF * sizeof(float)) return;  // ~18 MB

    const float* inp = (const float*)d_in[0];
    const float* w1  = (const float*)d_in[1];
    const float* w2  = (const float*)d_in[2];
    const float* wf1 = (const float*)d_in[3];
    const float* wf2 = (const float*)d_in[4];
    float* ws  = (float*)d_ws;
    float* out = (float*)d_out;

    k_encode<<<BATCH, 896, 0, stream>>>(inp, (unsigned*)(ws + o_inb), ws + o_cnt);
    k_conv1<<<2048 + 1862, 256, 0, stream>>>(w1, (const unsigned*)(ws + o_inb),
                                             (unsigned*)(ws + o_p1b),
                                             (unsigned short*)(ws + o_flag),
                                             wf1, ws + o_wt, ws + o_cnt);
    k_conv2<<<(BATCH / 4) * 32, 256, 0, stream>>>(w2, (const unsigned*)(ws + o_p1b),
                                                  (const unsigned short*)(ws + o_flag),
                                                  (unsigned short*)(ws + o_p2m), ws + o_cnt);
    k_fc1pre<<<16 * BATCH, 640, 0, stream>>>(ws + o_wt, (const unsigned short*)(ws + o_p2m),
                                             ws + o_c1, out);
    k_fc12b<<<BATCH, 640, 0, stream>>>(ws + o_c1, wf2, ws + o_cnt, out);
}